// Round 1
// baseline (1794.864 us; speedup 1.0000x reference)
//
#include <hip/hip_runtime.h>
#include <hip/hip_bf16.h>
#include <math.h>

#define B_ 2
#define H_ 16
#define N_ 8192
#define D_ 64
#define R_ 7
#define BLOCK_ 256
#define SAMPLE_ 256
#define BH_ (B_*H_)
#define NBLK_ (N_/BLOCK_)

// ---------------- Kernel 1: LSH hash (gray-coded bucket per row) ----------------
__global__ __launch_bounds__(256) void hash_kernel(
    const float* __restrict__ q, const float* __restrict__ k,
    const float* __restrict__ pd, int* __restrict__ qh, int* __restrict__ kh) {
  __shared__ float spd[D_ * R_];  // 448 floats
  for (int i = threadIdx.x; i < D_ * R_; i += blockDim.x) spd[i] = pd[i];
  __syncthreads();
  int tid = blockIdx.x * blockDim.x + threadIdx.x;  // 0 .. 2*BH*N-1
  const int half = BH_ * N_;
  const float* src = (tid < half) ? q : k;
  int* dst = (tid < half) ? qh : kh;
  int row = (tid < half) ? tid : tid - half;
  const float* x = src + (size_t)row * D_;
  float acc[R_];
#pragma unroll
  for (int r = 0; r < R_; r++) acc[r] = 0.f;
#pragma unroll
  for (int d = 0; d < D_; d++) {
    float xv = x[d];
#pragma unroll
    for (int r = 0; r < R_; r++) acc[r] = fmaf(xv, spd[d * R_ + r], acc[r]);
  }
  int bin = 0;
#pragma unroll
  for (int r = 0; r < R_; r++) bin |= (acc[r] > 0.f) ? (1 << r) : 0;
  dst[row] = bin ^ (bin >> 1);  // gray-code permutation
}

// ---------------- Kernel 2: stable counting sort per (b,h) ----------------
// grid = 2*BH blocks (first BH: q, next BH: k), 64 threads each.
__global__ __launch_bounds__(64) void sort_kernel(
    const int* __restrict__ qh, const int* __restrict__ kh,
    int* __restrict__ qidx, int* __restrict__ kidx) {
  int g = blockIdx.x;
  int bh = g & (BH_ - 1);
  bool isK = g >= BH_;
  const int* h = (isK ? kh : qh) + (size_t)bh * N_;
  int* idx = (isK ? kidx : qidx) + (size_t)bh * N_;
  __shared__ int hist[128][64];
  __shared__ int tot[128];
  __shared__ int off[128];
  int t = threadIdx.x;
  for (int b = 0; b < 128; b++) hist[b][t] = 0;
  __syncthreads();
  const int base = t * 128;  // each thread owns 128 consecutive positions
  for (int j = 0; j < 128; j++) hist[h[base + j]][t]++;
  __syncthreads();
  for (int b = t; b < 128; b += 64) {
    int s = 0;
    for (int tt = 0; tt < 64; tt++) s += hist[b][tt];
    tot[b] = s;
  }
  __syncthreads();
  if (t == 0) {
    int run = 0;
    for (int b = 0; b < 128; b++) { off[b] = run; run += tot[b]; }
  }
  __syncthreads();
  for (int b = t; b < 128; b += 64) {
    int run = off[b];
    for (int tt = 0; tt < 64; tt++) { int tmp = hist[b][tt]; hist[b][tt] = run; run += tmp; }
  }
  __syncthreads();
  for (int j = 0; j < 128; j++) {
    int c = h[base + j];
    idx[hist[c][t]++] = base + j;  // stable: thread order + in-thread order
  }
}

// ---------------- Kernel 3: gather sampled K/V (double indirection) ----------------
// grid = BH*SAMPLE blocks, 64 threads (one per d)
__global__ __launch_bounds__(64) void subgather_kernel(
    const float* __restrict__ key, const float* __restrict__ val,
    const int* __restrict__ kidx, const int* __restrict__ samp,
    float* __restrict__ ksub, float* __restrict__ vsub, int* __restrict__ sblk) {
  int g = blockIdx.x;
  int bh = g / SAMPLE_;
  int s = g - bh * SAMPLE_;
  int pos = samp[(size_t)bh * SAMPLE_ + s];       // index into sorted order
  int row = kidx[(size_t)bh * N_ + pos];          // original row
  int d = threadIdx.x;
  size_t srcb = ((size_t)bh * N_ + row) * D_ + d;
  size_t dstb = ((size_t)bh * SAMPLE_ + s) * D_ + d;
  ksub[dstb] = key[srcb];
  vsub[dstb] = val[srcb];
  if (d == 0) sblk[(size_t)bh * SAMPLE_ + s] = pos / BLOCK_;
}

// 64-d dot with 4 independent accumulator chains
__device__ inline float dot64(const float* __restrict__ qv, const float* __restrict__ kr) {
  float s0 = 0.f, s1 = 0.f, s2 = 0.f, s3 = 0.f;
#pragma unroll
  for (int d = 0; d < D_; d += 4) {
    s0 = fmaf(qv[d + 0], kr[d + 0], s0);
    s1 = fmaf(qv[d + 1], kr[d + 1], s1);
    s2 = fmaf(qv[d + 2], kr[d + 2], s2);
    s3 = fmaf(qv[d + 3], kr[d + 3], s3);
  }
  return (s0 + s1) + (s2 + s3);
}

// ---------------- Kernel 4: fused block-diagonal + sampled-residual attention ----------------
// grid = BH*NBLK blocks, 256 threads; thread-per-sorted-query; scatter to original order.
__global__ __launch_bounds__(256, 1) void attn_kernel(
    const float* __restrict__ query, const float* __restrict__ key,
    const float* __restrict__ value,
    const int* __restrict__ qidx, const int* __restrict__ kidx,
    const float* __restrict__ ksub, const float* __restrict__ vsub,
    const int* __restrict__ sblk, float* __restrict__ out) {
  __shared__ float Kt[BLOCK_][D_];   // 64 KiB
  __shared__ float Vt[BLOCK_][D_];   // 64 KiB
  __shared__ int sb[SAMPLE_];
  const int bh = blockIdx.x / NBLK_;
  const int blk = blockIdx.x - bh * NBLK_;
  const int tid = threadIdx.x;
  const float scale = 0.125f;  // 1/sqrt(64)

  // --- stage block K/V (gathered through k_sort_idx) ---
  {
    int krow = kidx[(size_t)bh * N_ + blk * BLOCK_ + tid];
    const float4* ksrc = (const float4*)(key + ((size_t)bh * N_ + krow) * D_);
    const float4* vsrc = (const float4*)(value + ((size_t)bh * N_ + krow) * D_);
    float4* kdst = (float4*)(&Kt[tid][0]);
    float4* vdst = (float4*)(&Vt[tid][0]);
#pragma unroll
    for (int j = 0; j < 16; j++) { kdst[j] = ksrc[j]; vdst[j] = vsrc[j]; }
  }
  // --- own query row into registers ---
  const int qrow = qidx[(size_t)bh * N_ + blk * BLOCK_ + tid];
  float qv[D_];
  {
    const float4* qsrc = (const float4*)(query + ((size_t)bh * N_ + qrow) * D_);
#pragma unroll
    for (int j = 0; j < 16; j++) {
      float4 v = qsrc[j];
      qv[4 * j + 0] = v.x; qv[4 * j + 1] = v.y; qv[4 * j + 2] = v.z; qv[4 * j + 3] = v.w;
    }
  }
  __syncthreads();

  // --- phase A: block attention, single pass (|s|<~6 so no max subtraction) ---
  float acc[D_];
#pragma unroll
  for (int d = 0; d < D_; d++) acc[d] = 0.f;
  float lb = 0.f;
  for (int k2 = 0; k2 < BLOCK_; k2++) {
    float s = dot64(qv, &Kt[k2][0]) * scale;
    float w = __expf(s);
    lb += w;
#pragma unroll
    for (int d = 0; d < D_; d++) acc[d] = fmaf(w, Vt[k2][d], acc[d]);
  }
  float lse_b = __logf(lb);
  float inv_lb = 1.f / lb;
  __syncthreads();

  // --- stage sampled K/V ---
  {
    const float4* ksrc = (const float4*)(ksub + ((size_t)bh * SAMPLE_ + tid) * D_);
    const float4* vsrc = (const float4*)(vsub + ((size_t)bh * SAMPLE_ + tid) * D_);
    float4* kdst = (float4*)(&Kt[tid][0]);
    float4* vdst = (float4*)(&Vt[tid][0]);
#pragma unroll
    for (int j = 0; j < 16; j++) { kdst[j] = ksrc[j]; vdst[j] = vsrc[j]; }
    sb[tid] = sblk[(size_t)bh * SAMPLE_ + tid];
  }
  __syncthreads();

  // --- phase B: sampled residual (skip colliding blocks == bias finfo.min) ---
  float racc[D_];
#pragma unroll
  for (int d = 0; d < D_; d++) racc[d] = 0.f;
  float lr = 0.f;
  for (int k2 = 0; k2 < SAMPLE_; k2++) {
    if (sb[k2] == blk) continue;  // wave-uniform branch
    float s = dot64(qv, &Kt[k2][0]) * scale;
    float w = __expf(s);
    lr += w;
#pragma unroll
    for (int d = 0; d < D_; d++) racc[d] = fmaf(w, Vt[k2][d], racc[d]);
  }

  float c, wr;
  if (lr > 0.f) {
    float lse_r = __logf(lr) + 3.4657359027997265f;  // + log(N/SAMPLE)=log 32
    c = 1.f / (1.f + __expf(lse_r - lse_b));          // sigmoid(lse_b - lse_r)
    wr = (1.f - c) / lr;
  } else {
    c = 1.f; wr = 0.f;
  }
  float wb = c * inv_lb;

  // --- merge + scatter to original query order ---
  float4* odst = (float4*)(out + ((size_t)bh * N_ + qrow) * D_);
#pragma unroll
  for (int j = 0; j < 16; j++) {
    float4 o;
    o.x = wb * acc[4 * j + 0] + wr * racc[4 * j + 0];
    o.y = wb * acc[4 * j + 1] + wr * racc[4 * j + 1];
    o.z = wb * acc[4 * j + 2] + wr * racc[4 * j + 2];
    o.w = wb * acc[4 * j + 3] + wr * racc[4 * j + 3];
    odst[j] = o;
  }
}

extern "C" void kernel_launch(void* const* d_in, const int* in_sizes, int n_in,
                              void* d_out, int out_size, void* d_ws, size_t ws_size,
                              hipStream_t stream) {
  const float* query = (const float*)d_in[0];
  const float* key   = (const float*)d_in[1];
  const float* value = (const float*)d_in[2];
  const float* pd    = (const float*)d_in[3];
  const int*   samp  = (const int*)d_in[4];
  float* out = (float*)d_out;

  char* w = (char*)d_ws;
  size_t o = 0;
  auto alloc = [&](size_t bytes) { void* p = w + o; o = (o + bytes + 255) & ~(size_t)255; return p; };
  int* qh   = (int*)alloc((size_t)BH_ * N_ * 4);
  int* kh   = (int*)alloc((size_t)BH_ * N_ * 4);
  int* qidx = (int*)alloc((size_t)BH_ * N_ * 4);
  int* kidx = (int*)alloc((size_t)BH_ * N_ * 4);
  float* ksub = (float*)alloc((size_t)BH_ * SAMPLE_ * D_ * 4);
  float* vsub = (float*)alloc((size_t)BH_ * SAMPLE_ * D_ * 4);
  int* sblk = (int*)alloc((size_t)BH_ * SAMPLE_ * 4);

  // 1) hash q and k
  hash_kernel<<<(2 * BH_ * N_) / 256, 256, 0, stream>>>(query, key, pd, qh, kh);
  // 2) stable sort both
  sort_kernel<<<2 * BH_, 64, 0, stream>>>(qh, kh, qidx, kidx);
  // 3) sampled K/V gather
  subgather_kernel<<<BH_ * SAMPLE_, 64, 0, stream>>>(key, value, kidx, samp, ksub, vsub, sblk);
  // 4) fused attention + merge + unsort
  attn_kernel<<<BH_ * NBLK_, 256, 0, stream>>>(query, key, value, qidx, kidx,
                                               ksub, vsub, sblk, out);
}

// Round 2
// 207.102 us; speedup vs baseline: 8.6666x; 8.6666x over previous
//
#include <hip/hip_runtime.h>
#include <hip/hip_bf16.h>
#include <math.h>

#define B_ 2
#define H_ 16
#define N_ 8192
#define D_ 64
#define R_ 7
#define BLOCK_ 256
#define SAMPLE_ 256
#define BH_ (B_*H_)
#define NBLK_ (N_/BLOCK_)

#define PADK 72    // Ks row elements (64+8)  -> 144 B row stride
#define PADV 264   // Vt row elements (256+8) -> 528 B row stride
#define PADW 72    // Ws row elements (64+8)

typedef __attribute__((ext_vector_type(8))) short bf16x8;
typedef __attribute__((ext_vector_type(4))) float f32x4;
typedef __attribute__((ext_vector_type(2))) unsigned int u32x2;
typedef __attribute__((ext_vector_type(4))) unsigned int u32x4;

__device__ inline unsigned short f2bf(float x) {
  union { float f; unsigned u; } v; v.f = x;
  return (unsigned short)((v.u + 0x7FFFu + ((v.u >> 16) & 1u)) >> 16);
}
__device__ inline unsigned int pack2bf(float a, float b) {
  union { float f; unsigned u; } x, y; x.f = a; y.f = b;
  unsigned lo = (x.u + 0x7FFFu + ((x.u >> 16) & 1u)) >> 16;
  unsigned hi = (y.u + 0x7FFFu + ((y.u >> 16) & 1u)) >> 16;
  return lo | (hi << 16);
}

// ---------------- Kernel 1: LSH hash (gray-coded bucket per row) ----------------
__global__ __launch_bounds__(256) void hash_kernel(
    const float* __restrict__ q, const float* __restrict__ k,
    const float* __restrict__ pd, int* __restrict__ qh, int* __restrict__ kh) {
  __shared__ float spd[D_ * R_];
  for (int i = threadIdx.x; i < D_ * R_; i += blockDim.x) spd[i] = pd[i];
  __syncthreads();
  int tid = blockIdx.x * blockDim.x + threadIdx.x;
  const int half = BH_ * N_;
  const float* src = (tid < half) ? q : k;
  int* dst = (tid < half) ? qh : kh;
  int row = (tid < half) ? tid : tid - half;
  const float* x = src + (size_t)row * D_;
  float acc[R_];
#pragma unroll
  for (int r = 0; r < R_; r++) acc[r] = 0.f;
#pragma unroll
  for (int d = 0; d < D_; d++) {
    float xv = x[d];
#pragma unroll
    for (int r = 0; r < R_; r++) acc[r] = fmaf(xv, spd[d * R_ + r], acc[r]);
  }
  int bin = 0;
#pragma unroll
  for (int r = 0; r < R_; r++) bin |= (acc[r] > 0.f) ? (1 << r) : 0;
  dst[row] = bin ^ (bin >> 1);
}

// ---------------- Kernel 2: stable counting sort per (b,h) ----------------
__global__ __launch_bounds__(64) void sort_kernel(
    const int* __restrict__ qh, const int* __restrict__ kh,
    int* __restrict__ qidx, int* __restrict__ kidx) {
  int g = blockIdx.x;
  int bh = g & (BH_ - 1);
  bool isK = g >= BH_;
  const int* h = (isK ? kh : qh) + (size_t)bh * N_;
  int* idx = (isK ? kidx : qidx) + (size_t)bh * N_;
  __shared__ int hist[128][64];
  __shared__ int tot[128];
  __shared__ int off[128];
  int t = threadIdx.x;
  for (int b = 0; b < 128; b++) hist[b][t] = 0;
  __syncthreads();
  const int base = t * 128;
  for (int j = 0; j < 128; j++) hist[h[base + j]][t]++;
  __syncthreads();
  for (int b = t; b < 128; b += 64) {
    int s = 0;
    for (int tt = 0; tt < 64; tt++) s += hist[b][tt];
    tot[b] = s;
  }
  __syncthreads();
  if (t == 0) {
    int run = 0;
    for (int b = 0; b < 128; b++) { off[b] = run; run += tot[b]; }
  }
  __syncthreads();
  for (int b = t; b < 128; b += 64) {
    int run = off[b];
    for (int tt = 0; tt < 64; tt++) { int tmp = hist[b][tt]; hist[b][tt] = run; run += tmp; }
  }
  __syncthreads();
  for (int j = 0; j < 128; j++) {
    int c = h[base + j];
    idx[hist[c][t]++] = base + j;
  }
}

// ---------------- Kernel 3: gather sampled K/V (double indirection) ----------------
__global__ __launch_bounds__(64) void subgather_kernel(
    const float* __restrict__ key, const float* __restrict__ val,
    const int* __restrict__ kidx, const int* __restrict__ samp,
    float* __restrict__ ksub, float* __restrict__ vsub, int* __restrict__ sblk) {
  int g = blockIdx.x;
  int bh = g / SAMPLE_;
  int s = g - bh * SAMPLE_;
  int pos = samp[(size_t)bh * SAMPLE_ + s];
  int row = kidx[(size_t)bh * N_ + pos];
  int d = threadIdx.x;
  size_t srcb = ((size_t)bh * N_ + row) * D_ + d;
  size_t dstb = ((size_t)bh * SAMPLE_ + s) * D_ + d;
  ksub[dstb] = key[srcb];
  vsub[dstb] = val[srcb];
  if (d == 0) sblk[(size_t)bh * SAMPLE_ + s] = pos / BLOCK_;
}

// ---------------- Kernel 4: MFMA fused attention ----------------
// grid = BH*NBLK, 256 threads (4 waves). Wave w owns queries [w*64, w*64+64).
// Phase A: block-diagonal attention.  Phase B: sampled residual (masked).
// S^T = K x Q^T via mfma(A=K_frag, B=Q_frag): C col=q(lane&15), row=k((lane>>4)*4+reg)
//  -> 4 consecutive k per lane -> pack bf16 pairs -> ds_write_b64 into W[q][k] (wave-private)
// PV: O = W x V via mfma(A=W_frag(b128), B=Vt_frag(b128 from transposed V))
__global__ __launch_bounds__(256, 1) void attn_kernel(
    const float* __restrict__ query, const float* __restrict__ key,
    const float* __restrict__ value,
    const int* __restrict__ qidx, const int* __restrict__ kidx,
    const float* __restrict__ ksub, const float* __restrict__ vsub,
    const int* __restrict__ sblk, float* __restrict__ out) {
  __shared__ __align__(16) unsigned short KsL[BLOCK_ * PADK];   // 36864 B
  __shared__ __align__(16) unsigned short VtL[D_ * PADV];       // 33792 B
  __shared__ __align__(16) unsigned short WsL[4 * 64 * PADW];   // 36864 B
  __shared__ int sbs[SAMPLE_];
  __shared__ int qrows[BLOCK_];

  const int bh = blockIdx.x / NBLK_;
  const int blk = blockIdx.x - bh * NBLK_;
  const int tid = threadIdx.x;
  const int w = tid >> 6;
  const int lane = tid & 63;
  const int lg = lane >> 4;    // lane group 0..3
  const int lr = lane & 15;
  const float scale = 0.125f;
  unsigned short* Wm = WsL + w * (64 * PADW);

  // ---- stage block K (bf16 row-major) and V (bf16 transposed), qrows ----
  {
    int krow = kidx[(size_t)bh * N_ + blk * BLOCK_ + tid];
    const float4* src = (const float4*)(key + ((size_t)bh * N_ + krow) * D_);
    unsigned up[32];
#pragma unroll
    for (int j = 0; j < 16; j++) {
      float4 v = src[j];
      up[2 * j] = pack2bf(v.x, v.y); up[2 * j + 1] = pack2bf(v.z, v.w);
    }
    u32x4* dst = (u32x4*)&KsL[tid * PADK];
#pragma unroll
    for (int j = 0; j < 8; j++) dst[j] = (u32x4){up[4 * j], up[4 * j + 1], up[4 * j + 2], up[4 * j + 3]};
    const float4* vs = (const float4*)(value + ((size_t)bh * N_ + krow) * D_);
#pragma unroll
    for (int j = 0; j < 16; j++) {
      float4 v = vs[j];
      VtL[(4 * j + 0) * PADV + tid] = f2bf(v.x);
      VtL[(4 * j + 1) * PADV + tid] = f2bf(v.y);
      VtL[(4 * j + 2) * PADV + tid] = f2bf(v.z);
      VtL[(4 * j + 3) * PADV + tid] = f2bf(v.w);
    }
    qrows[tid] = qidx[(size_t)bh * N_ + blk * BLOCK_ + tid];
  }
  __syncthreads();

  // ---- Q fragments in registers: qf[qt][h], lane holds Q[row=lr][lg*8 + h*32 ..+8] ----
  bf16x8 qf[4][2];
#pragma unroll
  for (int qt = 0; qt < 4; qt++) {
    int qrow = qrows[w * 64 + qt * 16 + lr];
    const float* qp = query + ((size_t)bh * N_ + qrow) * D_ + lg * 8;
#pragma unroll
    for (int h = 0; h < 2; h++) {
      float4 a = *(const float4*)(qp + h * 32);
      float4 b = *(const float4*)(qp + h * 32 + 4);
      union { u32x4 u; bf16x8 v; } cv;
      cv.u = (u32x4){pack2bf(a.x, a.y), pack2bf(a.z, a.w), pack2bf(b.x, b.y), pack2bf(b.z, b.w)};
      qf[qt][h] = cv.v;
    }
  }

  f32x4 oA[4][4], oB[4][4];
  float lsA[4] = {0.f, 0.f, 0.f, 0.f}, lsB[4] = {0.f, 0.f, 0.f, 0.f};
#pragma unroll
  for (int a = 0; a < 4; a++)
#pragma unroll
    for (int b = 0; b < 4; b++) { oA[a][b] = (f32x4){0.f,0.f,0.f,0.f}; oB[a][b] = (f32x4){0.f,0.f,0.f,0.f}; }

  // ---- one phase: 4 chunks of 64 keys: S^T -> exp(+mask) -> W LDS -> PV ----
  auto phase = [&](f32x4 (&o)[4][4], float (&ls)[4], bool masked) {
    for (int kc = 0; kc < 4; kc++) {
#pragma unroll
      for (int kt = 0; kt < 4; kt++) {
        const unsigned short* krow = &KsL[(kc * 64 + kt * 16 + lr) * PADK + lg * 8];
        bf16x8 ak0 = *(const bf16x8*)(krow);
        bf16x8 ak1 = *(const bf16x8*)(krow + 32);
        float msk[4];
        if (masked) {
#pragma unroll
          for (int r = 0; r < 4; r++)
            msk[r] = (sbs[kc * 64 + kt * 16 + lg * 4 + r] == blk) ? 0.f : 1.f;
        }
#pragma unroll
        for (int qt = 0; qt < 4; qt++) {
          f32x4 c = (f32x4){0.f, 0.f, 0.f, 0.f};
          c = __builtin_amdgcn_mfma_f32_16x16x32_bf16(ak0, qf[qt][0], c, 0, 0, 0);
          c = __builtin_amdgcn_mfma_f32_16x16x32_bf16(ak1, qf[qt][1], c, 0, 0, 0);
          float w0 = __expf(c[0] * scale), w1 = __expf(c[1] * scale);
          float w2 = __expf(c[2] * scale), w3 = __expf(c[3] * scale);
          if (masked) { w0 *= msk[0]; w1 *= msk[1]; w2 *= msk[2]; w3 *= msk[3]; }
          ls[qt] += (w0 + w1) + (w2 + w3);
          // W[q=qt*16+lr][k=kt*16+lg*4 .. +4]
          u32x2 p = (u32x2){pack2bf(w0, w1), pack2bf(w2, w3)};
          *(u32x2*)(&Wm[(qt * 16 + lr) * PADW + kt * 16 + lg * 4]) = p;
        }
      }
      // PV for this chunk (wave-private W: compiler inserts lgkmcnt waits)
#pragma unroll
      for (int h2 = 0; h2 < 2; h2++) {
        bf16x8 aw[4], bv[4];
#pragma unroll
        for (int qt = 0; qt < 4; qt++)
          aw[qt] = *(const bf16x8*)(&Wm[(qt * 16 + lr) * PADW + h2 * 32 + lg * 8]);
#pragma unroll
        for (int dt = 0; dt < 4; dt++)
          bv[dt] = *(const bf16x8*)(&VtL[(dt * 16 + lr) * PADV + kc * 64 + h2 * 32 + lg * 8]);
#pragma unroll
        for (int qt = 0; qt < 4; qt++)
#pragma unroll
          for (int dt = 0; dt < 4; dt++)
            o[qt][dt] = __builtin_amdgcn_mfma_f32_16x16x32_bf16(aw[qt], bv[dt], o[qt][dt], 0, 0, 0);
      }
    }
  };

  phase(oA, lsA, false);
  __syncthreads();

  // ---- restage sampled K/V ----
  {
    const float4* src = (const float4*)(ksub + ((size_t)bh * SAMPLE_ + tid) * D_);
    unsigned up[32];
#pragma unroll
    for (int j = 0; j < 16; j++) {
      float4 v = src[j];
      up[2 * j] = pack2bf(v.x, v.y); up[2 * j + 1] = pack2bf(v.z, v.w);
    }
    u32x4* dst = (u32x4*)&KsL[tid * PADK];
#pragma unroll
    for (int j = 0; j < 8; j++) dst[j] = (u32x4){up[4 * j], up[4 * j + 1], up[4 * j + 2], up[4 * j + 3]};
    const float4* vs = (const float4*)(vsub + ((size_t)bh * SAMPLE_ + tid) * D_);
#pragma unroll
    for (int j = 0; j < 16; j++) {
      float4 v = vs[j];
      VtL[(4 * j + 0) * PADV + tid] = f2bf(v.x);
      VtL[(4 * j + 1) * PADV + tid] = f2bf(v.y);
      VtL[(4 * j + 2) * PADV + tid] = f2bf(v.z);
      VtL[(4 * j + 3) * PADV + tid] = f2bf(v.w);
    }
    sbs[tid] = sblk[(size_t)bh * SAMPLE_ + tid];
  }
  __syncthreads();

  phase(oB, lsB, true);

  // ---- merge + scatter ----
#pragma unroll
  for (int qt = 0; qt < 4; qt++) {
    float lb = lsA[qt];
    lb += __shfl_xor(lb, 16); lb += __shfl_xor(lb, 32);
    float lrv = lsB[qt];
    lrv += __shfl_xor(lrv, 16); lrv += __shfl_xor(lrv, 32);
    float wb, wr;
    float lseb = __logf(lb);
    if (lrv > 0.f) {
      float lser = __logf(lrv) + 3.4657359027997265f;  // + log(32)
      float cc = 1.f / (1.f + __expf(lser - lseb));
      wb = cc / lb; wr = (1.f - cc) / lrv;
    } else {
      wb = 1.f / lb; wr = 0.f;
    }
#pragma unroll
    for (int r = 0; r < 4; r++) {
      float wbr = __shfl(wb, lg * 4 + r);
      float wrr = __shfl(wr, lg * 4 + r);
      int qr = qrows[w * 64 + qt * 16 + lg * 4 + r];
      float* op = out + ((size_t)bh * N_ + qr) * D_ + lr;
#pragma unroll
      for (int dt = 0; dt < 4; dt++)
        op[dt * 16] = wbr * oA[qt][dt][r] + wrr * oB[qt][dt][r];
    }
  }
}

extern "C" void kernel_launch(void* const* d_in, const int* in_sizes, int n_in,
                              void* d_out, int out_size, void* d_ws, size_t ws_size,
                              hipStream_t stream) {
  const float* query = (const float*)d_in[0];
  const float* key   = (const float*)d_in[1];
  const float* value = (const float*)d_in[2];
  const float* pd    = (const float*)d_in[3];
  const int*   samp  = (const int*)d_in[4];
  float* out = (float*)d_out;

  char* w = (char*)d_ws;
  size_t o = 0;
  auto alloc = [&](size_t bytes) { void* p = w + o; o = (o + bytes + 255) & ~(size_t)255; return p; };
  int* qh   = (int*)alloc((size_t)BH_ * N_ * 4);
  int* kh   = (int*)alloc((size_t)BH_ * N_ * 4);
  int* qidx = (int*)alloc((size_t)BH_ * N_ * 4);
  int* kidx = (int*)alloc((size_t)BH_ * N_ * 4);
  float* ksub = (float*)alloc((size_t)BH_ * SAMPLE_ * D_ * 4);
  float* vsub = (float*)alloc((size_t)BH_ * SAMPLE_ * D_ * 4);
  int* sblk = (int*)alloc((size_t)BH_ * SAMPLE_ * 4);

  hash_kernel<<<(2 * BH_ * N_) / 256, 256, 0, stream>>>(query, key, pd, qh, kh);
  sort_kernel<<<2 * BH_, 64, 0, stream>>>(qh, kh, qidx, kidx);
  subgather_kernel<<<BH_ * SAMPLE_, 64, 0, stream>>>(key, value, kidx, samp, ksub, vsub, sblk);
  attn_kernel<<<BH_ * NBLK_, 256, 0, stream>>>(query, key, value, qidx, kidx,
                                               ksub, vsub, sblk, out);
}

// Round 3
// 171.539 us; speedup vs baseline: 10.4633x; 1.2073x over previous
//
#include <hip/hip_runtime.h>
#include <hip/hip_bf16.h>
#include <math.h>

#define B_ 2
#define H_ 16
#define N_ 8192
#define D_ 64
#define R_ 7
#define BLOCK_ 256
#define SAMPLE_ 256
#define BH_ (B_*H_)
#define NBLK_ (N_/BLOCK_)

#define PADK 72    // Ks row elements (64+8)  -> 144 B row stride (2-way max on b128 reads)
#define PADV 260   // Vt row elements (256+4) -> 520 B row stride (conflict-free b64 A-frag reads)

typedef __attribute__((ext_vector_type(8))) short bf16x8;
typedef __attribute__((ext_vector_type(4))) short bf16x4;
typedef __attribute__((ext_vector_type(4))) float f32x4;
typedef __attribute__((ext_vector_type(2))) unsigned int u32x2;
typedef __attribute__((ext_vector_type(4))) unsigned int u32x4;

__device__ inline unsigned short f2bf(float x) {
  union { float f; unsigned u; } v; v.f = x;
  return (unsigned short)((v.u + 0x7FFFu + ((v.u >> 16) & 1u)) >> 16);
}
__device__ inline unsigned int pack2bf(float a, float b) {
  union { float f; unsigned u; } x, y; x.f = a; y.f = b;
  unsigned lo = (x.u + 0x7FFFu + ((x.u >> 16) & 1u)) >> 16;
  unsigned hi = (y.u + 0x7FFFu + ((y.u >> 16) & 1u)) >> 16;
  return lo | (hi << 16);
}

// PV mfma: D = A(16x16: d x k) * B(16x16: k x q), K=16, bf16
__device__ inline f32x4 mfma16(bf16x4 a, bf16x4 b, f32x4 c) {
#if __has_builtin(__builtin_amdgcn_mfma_f32_16x16x16bf16_1k)
  return __builtin_amdgcn_mfma_f32_16x16x16bf16_1k(a, b, c, 0, 0, 0);
#else
  asm volatile("v_mfma_f32_16x16x16_bf16 %0, %1, %2, %0" : "+v"(c) : "v"(a), "v"(b));
  return c;
#endif
}

// ---------------- Kernel 1: LSH hash (gray-coded bucket per row) ----------------
__global__ __launch_bounds__(256) void hash_kernel(
    const float* __restrict__ q, const float* __restrict__ k,
    const float* __restrict__ pd, int* __restrict__ qh, int* __restrict__ kh) {
  __shared__ float spd[D_ * R_];
  for (int i = threadIdx.x; i < D_ * R_; i += blockDim.x) spd[i] = pd[i];
  __syncthreads();
  int tid = blockIdx.x * blockDim.x + threadIdx.x;
  const int half = BH_ * N_;
  const float* src = (tid < half) ? q : k;
  int* dst = (tid < half) ? qh : kh;
  int row = (tid < half) ? tid : tid - half;
  const float4* x4 = (const float4*)(src + (size_t)row * D_);
  float acc[R_];
#pragma unroll
  for (int r = 0; r < R_; r++) acc[r] = 0.f;
#pragma unroll
  for (int j = 0; j < 16; j++) {
    float4 v = x4[j];
#pragma unroll
    for (int r = 0; r < R_; r++) {
      acc[r] = fmaf(v.x, spd[(4 * j + 0) * R_ + r], acc[r]);
      acc[r] = fmaf(v.y, spd[(4 * j + 1) * R_ + r], acc[r]);
      acc[r] = fmaf(v.z, spd[(4 * j + 2) * R_ + r], acc[r]);
      acc[r] = fmaf(v.w, spd[(4 * j + 3) * R_ + r], acc[r]);
    }
  }
  int bin = 0;
#pragma unroll
  for (int r = 0; r < R_; r++) bin |= (acc[r] > 0.f) ? (1 << r) : 0;
  dst[row] = bin ^ (bin >> 1);
}

// ---------------- Kernel 2: stable counting sort per (b,h) ----------------
__global__ __launch_bounds__(64) void sort_kernel(
    const int* __restrict__ qh, const int* __restrict__ kh,
    int* __restrict__ qidx, int* __restrict__ kidx) {
  int g = blockIdx.x;
  int bh = g & (BH_ - 1);
  bool isK = g >= BH_;
  const int* h = (isK ? kh : qh) + (size_t)bh * N_;
  int* idx = (isK ? kidx : qidx) + (size_t)bh * N_;
  __shared__ int hist[128][64];
  __shared__ int tot[128];
  __shared__ int off[128];
  int t = threadIdx.x;
  for (int b = 0; b < 128; b++) hist[b][t] = 0;
  __syncthreads();
  const int base = t * 128;
  for (int j = 0; j < 128; j++) hist[h[base + j]][t]++;
  __syncthreads();
  for (int b = t; b < 128; b += 64) {
    int s = 0;
    for (int tt = 0; tt < 64; tt++) s += hist[b][tt];
    tot[b] = s;
  }
  __syncthreads();
  if (t == 0) {
    int run = 0;
    for (int b = 0; b < 128; b++) { off[b] = run; run += tot[b]; }
  }
  __syncthreads();
  for (int b = t; b < 128; b += 64) {
    int run = off[b];
    for (int tt = 0; tt < 64; tt++) { int tmp = hist[b][tt]; hist[b][tt] = run; run += tmp; }
  }
  __syncthreads();
  for (int j = 0; j < 128; j++) {
    int c = h[base + j];
    idx[hist[c][t]++] = base + j;
  }
}

// ---------------- Kernel 3: gather sampled K/V (double indirection) ----------------
__global__ __launch_bounds__(64) void subgather_kernel(
    const float* __restrict__ key, const float* __restrict__ val,
    const int* __restrict__ kidx, const int* __restrict__ samp,
    float* __restrict__ ksub, float* __restrict__ vsub, int* __restrict__ sblk) {
  int g = blockIdx.x;
  int bh = g / SAMPLE_;
  int s = g - bh * SAMPLE_;
  int pos = samp[(size_t)bh * SAMPLE_ + s];
  int row = kidx[(size_t)bh * N_ + pos];
  int d = threadIdx.x;
  size_t srcb = ((size_t)bh * N_ + row) * D_ + d;
  size_t dstb = ((size_t)bh * SAMPLE_ + s) * D_ + d;
  ksub[dstb] = key[srcb];
  vsub[dstb] = val[srcb];
  if (d == 0) sblk[(size_t)bh * SAMPLE_ + s] = pos / BLOCK_;
}

// ---------------- Kernel 4: MFMA fused attention (no W round-trip) ----------------
// grid = BH*NBLK, 256 threads (4 waves). Wave w owns queries [w*64, w*64+64).
// QK: S^T = K x Q^T via mfma_16x16x32(A=K, B=Q). Lane holds S[q=lr][k=kt*16+lg*4+r].
// exp'd scores packed to bf16x4 == EXACTLY the B-fragment of mfma_16x16x16.
// PV: O^T = V^T x W via mfma_16x16x16(A=Vt b64 frags, B=score frags in reg).
// Lane ends with O^T[d=dt*16+lg*4+r][q=qt*16+lr] -> float4 stores.
__global__ __launch_bounds__(256, 2) void attn_kernel(
    const float* __restrict__ query, const float* __restrict__ key,
    const float* __restrict__ value,
    const int* __restrict__ qidx, const int* __restrict__ kidx,
    const float* __restrict__ ksub, const float* __restrict__ vsub,
    const int* __restrict__ sblk, float* __restrict__ out) {
  __shared__ __align__(16) unsigned short KsL[BLOCK_ * PADK];   // 36864 B
  __shared__ __align__(16) unsigned short VtL[D_ * PADV];       // 33280 B
  __shared__ int sbs[SAMPLE_];
  __shared__ int qrows[BLOCK_];

  const int bh = blockIdx.x / NBLK_;
  const int blk = blockIdx.x - bh * NBLK_;
  const int tid = threadIdx.x;
  const int w = tid >> 6;
  const int lane = tid & 63;
  const int lg = lane >> 4;
  const int lr = lane & 15;
  const float scale = 0.125f;

  // ---- stage block K (bf16 row-major) and V (bf16 transposed), qrows ----
  {
    int krow = kidx[(size_t)bh * N_ + blk * BLOCK_ + tid];
    const float4* src = (const float4*)(key + ((size_t)bh * N_ + krow) * D_);
    unsigned up[32];
#pragma unroll
    for (int j = 0; j < 16; j++) {
      float4 v = src[j];
      up[2 * j] = pack2bf(v.x, v.y); up[2 * j + 1] = pack2bf(v.z, v.w);
    }
    u32x4* dst = (u32x4*)&KsL[tid * PADK];
#pragma unroll
    for (int j = 0; j < 8; j++) dst[j] = (u32x4){up[4 * j], up[4 * j + 1], up[4 * j + 2], up[4 * j + 3]};
    const float4* vs = (const float4*)(value + ((size_t)bh * N_ + krow) * D_);
#pragma unroll
    for (int j = 0; j < 16; j++) {
      float4 v = vs[j];
      VtL[(4 * j + 0) * PADV + tid] = f2bf(v.x);
      VtL[(4 * j + 1) * PADV + tid] = f2bf(v.y);
      VtL[(4 * j + 2) * PADV + tid] = f2bf(v.z);
      VtL[(4 * j + 3) * PADV + tid] = f2bf(v.w);
    }
    qrows[tid] = qidx[(size_t)bh * N_ + blk * BLOCK_ + tid];
  }
  __syncthreads();

  // ---- Q fragments: qf[qt][h], lane holds Q[q=qt*16+lr][d = lg*8 + h*32 ..+8] ----
  bf16x8 qf[4][2];
#pragma unroll
  for (int qt = 0; qt < 4; qt++) {
    int qrow = qrows[w * 64 + qt * 16 + lr];
    const float* qp = query + ((size_t)bh * N_ + qrow) * D_ + lg * 8;
#pragma unroll
    for (int h = 0; h < 2; h++) {
      float4 a = *(const float4*)(qp + h * 32);
      float4 b = *(const float4*)(qp + h * 32 + 4);
      union { u32x4 u; bf16x8 v; } cv;
      cv.u = (u32x4){pack2bf(a.x, a.y), pack2bf(a.z, a.w), pack2bf(b.x, b.y), pack2bf(b.z, b.w)};
      qf[qt][h] = cv.v;
    }
  }

  f32x4 oA[4][4], oB[4][4];
  float lsA[4] = {0.f, 0.f, 0.f, 0.f}, lsB[4] = {0.f, 0.f, 0.f, 0.f};
#pragma unroll
  for (int a = 0; a < 4; a++)
#pragma unroll
    for (int b = 0; b < 4; b++) { oA[a][b] = (f32x4){0.f,0.f,0.f,0.f}; oB[a][b] = (f32x4){0.f,0.f,0.f,0.f}; }

  // ---- phase: per 16-key tile: QK mfma -> exp (+mask) -> pack -> PV mfma ----
  auto phase = [&](f32x4 (&o)[4][4], float (&ls)[4], bool masked) {
#pragma unroll 1
    for (int kt = 0; kt < 16; kt++) {
      const unsigned short* krow = &KsL[(kt * 16 + lr) * PADK + lg * 8];
      bf16x8 ak0 = *(const bf16x8*)(krow);
      bf16x8 ak1 = *(const bf16x8*)(krow + 32);
      bf16x4 av[4];
#pragma unroll
      for (int dt = 0; dt < 4; dt++)
        av[dt] = *(const bf16x4*)(&VtL[(dt * 16 + lr) * PADV + kt * 16 + lg * 4]);
      float msk[4];
      if (masked) {
#pragma unroll
        for (int r = 0; r < 4; r++)
          msk[r] = (sbs[kt * 16 + lg * 4 + r] == blk) ? 0.f : 1.f;
      }
      bf16x4 bq[4];
#pragma unroll
      for (int qt = 0; qt < 4; qt++) {
        f32x4 c = (f32x4){0.f, 0.f, 0.f, 0.f};
        c = __builtin_amdgcn_mfma_f32_16x16x32_bf16(ak0, qf[qt][0], c, 0, 0, 0);
        c = __builtin_amdgcn_mfma_f32_16x16x32_bf16(ak1, qf[qt][1], c, 0, 0, 0);
        float w0 = __expf(c[0] * scale), w1 = __expf(c[1] * scale);
        float w2 = __expf(c[2] * scale), w3 = __expf(c[3] * scale);
        if (masked) { w0 *= msk[0]; w1 *= msk[1]; w2 *= msk[2]; w3 *= msk[3]; }
        ls[qt] += (w0 + w1) + (w2 + w3);
        union { u32x2 u; bf16x4 v; } cv;
        cv.u = (u32x2){pack2bf(w0, w1), pack2bf(w2, w3)};
        bq[qt] = cv.v;
      }
#pragma unroll
      for (int qt = 0; qt < 4; qt++)
#pragma unroll
        for (int dt = 0; dt < 4; dt++)
          o[qt][dt] = mfma16(av[dt], bq[qt], o[qt][dt]);
    }
  };

  phase(oA, lsA, false);
  __syncthreads();

  // ---- restage sampled K/V ----
  {
    const float4* src = (const float4*)(ksub + ((size_t)bh * SAMPLE_ + tid) * D_);
    unsigned up[32];
#pragma unroll
    for (int j = 0; j < 16; j++) {
      float4 v = src[j];
      up[2 * j] = pack2bf(v.x, v.y); up[2 * j + 1] = pack2bf(v.z, v.w);
    }
    u32x4* dst = (u32x4*)&KsL[tid * PADK];
#pragma unroll
    for (int j = 0; j < 8; j++) dst[j] = (u32x4){up[4 * j], up[4 * j + 1], up[4 * j + 2], up[4 * j + 3]};
    const float4* vs = (const float4*)(vsub + ((size_t)bh * SAMPLE_ + tid) * D_);
#pragma unroll
    for (int j = 0; j < 16; j++) {
      float4 v = vs[j];
      VtL[(4 * j + 0) * PADV + tid] = f2bf(v.x);
      VtL[(4 * j + 1) * PADV + tid] = f2bf(v.y);
      VtL[(4 * j + 2) * PADV + tid] = f2bf(v.z);
      VtL[(4 * j + 3) * PADV + tid] = f2bf(v.w);
    }
    sbs[tid] = sblk[(size_t)bh * SAMPLE_ + tid];
  }
  __syncthreads();

  phase(oB, lsB, true);

  // ---- merge + scatter (lane owns q = qt*16+lr, d = dt*16+lg*4..+4) ----
#pragma unroll
  for (int qt = 0; qt < 4; qt++) {
    float lb = lsA[qt];
    lb += __shfl_xor(lb, 16); lb += __shfl_xor(lb, 32);
    float lrv = lsB[qt];
    lrv += __shfl_xor(lrv, 16); lrv += __shfl_xor(lrv, 32);
    float wb, wr;
    float lseb = __logf(lb);
    if (lrv > 0.f) {
      float lser = __logf(lrv) + 3.4657359027997265f;  // + log(32)
      float cc = 1.f / (1.f + __expf(lser - lseb));
      wb = cc / lb; wr = (1.f - cc) / lrv;
    } else {
      wb = 1.f / lb; wr = 0.f;
    }
    int qr = qrows[w * 64 + qt * 16 + lr];
    float* op = out + ((size_t)bh * N_ + qr) * D_ + lg * 4;
#pragma unroll
    for (int dt = 0; dt < 4; dt++) {
      float4 o;
      o.x = wb * oA[qt][dt][0] + wr * oB[qt][dt][0];
      o.y = wb * oA[qt][dt][1] + wr * oB[qt][dt][1];
      o.z = wb * oA[qt][dt][2] + wr * oB[qt][dt][2];
      o.w = wb * oA[qt][dt][3] + wr * oB[qt][dt][3];
      *(float4*)(op + dt * 16) = o;
    }
  }
}

extern "C" void kernel_launch(void* const* d_in, const int* in_sizes, int n_in,
                              void* d_out, int out_size, void* d_ws, size_t ws_size,
                              hipStream_t stream) {
  const float* query = (const float*)d_in[0];
  const float* key   = (const float*)d_in[1];
  const float* value = (const float*)d_in[2];
  const float* pd    = (const float*)d_in[3];
  const int*   samp  = (const int*)d_in[4];
  float* out = (float*)d_out;

  char* w = (char*)d_ws;
  size_t o = 0;
  auto alloc = [&](size_t bytes) { void* p = w + o; o = (o + bytes + 255) & ~(size_t)255; return p; };
  int* qh   = (int*)alloc((size_t)BH_ * N_ * 4);
  int* kh   = (int*)alloc((size_t)BH_ * N_ * 4);
  int* qidx = (int*)alloc((size_t)BH_ * N_ * 4);
  int* kidx = (int*)alloc((size_t)BH_ * N_ * 4);
  float* ksub = (float*)alloc((size_t)BH_ * SAMPLE_ * D_ * 4);
  float* vsub = (float*)alloc((size_t)BH_ * SAMPLE_ * D_ * 4);
  int* sblk = (int*)alloc((size_t)BH_ * SAMPLE_ * 4);

  hash_kernel<<<(2 * BH_ * N_) / 256, 256, 0, stream>>>(query, key, pd, qh, kh);
  sort_kernel<<<2 * BH_, 64, 0, stream>>>(qh, kh, qidx, kidx);
  subgather_kernel<<<BH_ * SAMPLE_, 64, 0, stream>>>(key, value, kidx, samp, ksub, vsub, sblk);
  attn_kernel<<<BH_ * NBLK_, 256, 0, stream>>>(query, key, value, qidx, kidx,
                                               ksub, vsub, sblk, out);
}